// Round 11
// baseline (399.067 us; speedup 1.0000x reference)
//
#include <hip/hip_runtime.h>
#include <hip/hip_bf16.h>

typedef __hip_bfloat16 bf16_t;
typedef __attribute__((ext_vector_type(8))) __bf16 bf16x8;
typedef __attribute__((ext_vector_type(4))) float f32x4;
typedef __attribute__((ext_vector_type(8))) unsigned short u16x8;

// ---------------------------------------------------------------- helpers

__device__ __forceinline__ void gld_lds16(const void* g, void* l) {
    // async global->LDS, 16B per lane. LDS dest is wave-uniform base + lane*16.
    __builtin_amdgcn_global_load_lds(
        (const __attribute__((address_space(1))) unsigned int*)g,
        (__attribute__((address_space(3))) unsigned int*)l,
        16, 0, 0);
}

__device__ __forceinline__ unsigned short bf16_bits(float x) {
    bf16_t b = __float2bfloat16(x);
    return *reinterpret_cast<unsigned short*>(&b);
}

// ---------------------------------------------------------------- convert x -> bf16

__global__ __launch_bounds__(256) void cvt_f32_bf16_kernel(
    const float* __restrict__ in, bf16_t* __restrict__ out, long n4) {
    long stride = (long)gridDim.x * blockDim.x;
    for (long i = (long)blockIdx.x * blockDim.x + threadIdx.x; i < n4; i += stride) {
        float4 v = reinterpret_cast<const float4*>(in)[i];
        ushort4 o;
        o.x = bf16_bits(v.x);
        o.y = bf16_bits(v.y);
        o.z = bf16_bits(v.z);
        o.w = bf16_bits(v.w);
        reinterpret_cast<ushort4*>(out)[i] = o;
    }
}

// ---------------------------------------------------------------- transposes

__global__ __launch_bounds__(256) void transpose_f32_bf16_kernel(
    const float* __restrict__ in, bf16_t* __restrict__ out, long ldin, long ldout) {
    __shared__ float tile[32][33];
    int c0 = blockIdx.x * 32, r0 = blockIdx.y * 32;
    int x = threadIdx.x;
#pragma unroll
    for (int yy = 0; yy < 4; ++yy) {
        int y = threadIdx.y + yy * 8;
        tile[y][x] = in[(long)(r0 + y) * ldin + c0 + x];
    }
    __syncthreads();
#pragma unroll
    for (int yy = 0; yy < 4; ++yy) {
        int y = threadIdx.y + yy * 8;
        out[(long)(c0 + y) * ldout + r0 + x] = __float2bfloat16(tile[x][y]);
    }
}

__global__ __launch_bounds__(256) void transpose_bf16_kernel(
    const bf16_t* __restrict__ in, bf16_t* __restrict__ out,
    long ldin, long ldout, long sIn, long sOut) {
    __shared__ bf16_t tile[32][33];
    in  += (long)blockIdx.z * sIn;
    out += (long)blockIdx.z * sOut;
    int c0 = blockIdx.x * 32, r0 = blockIdx.y * 32;
    int x = threadIdx.x;
#pragma unroll
    for (int yy = 0; yy < 4; ++yy) {
        int y = threadIdx.y + yy * 8;
        tile[y][x] = in[(long)(r0 + y) * ldin + c0 + x];
    }
    __syncthreads();
#pragma unroll
    for (int yy = 0; yy < 4; ++yy) {
        int y = threadIdx.y + yy * 8;
        out[(long)(c0 + y) * ldout + r0 + x] = tile[x][y];
    }
}

// ---------------------------------------------------------------- 256x256 8-wave GEMM, 4-phase/pair pipeline
// C[M,N] = scale*(A[M,K] @ Bt[N,K]^T) + bias[N]
// 512 threads = 8 waves (2M x 4N); per-wave 128x64 output; BK=32 subtiles
// processed in PAIRS (e=2u, o=2u+1), 4 phases per pair, 16 MFMA per phase:
//   ph0: read A-lo(e)+B(e) [8 ds_read] | stage A(e+2) | MFMA m0-3      | bar
//   ph1: read A-hi(e)      [4 ds_read] | stage B(e+2) | MFMA m4-7      | vmcnt(4) bar
//   ph2: read A-lo(o)+B(o) [8]         | stage A(o+2) | MFMA m0-3      | bar
//   ph3: read A-hi(o)      [4]         | stage B(o+2) | MFMA m4-7      | vmcnt(4) bar
// LDS: 4 rotating subtile slots per matrix (slot = subtile&3) = 128 KiB,
// XOR-swizzled (zero-conflict measured), inverse-swizzled global source.
// Counted vmcnt(4) twice per pair, never drained; each waited half-tile was
// issued 2 phases earlier. Barrier ALWAYS after vmcnt, before dependent
// reads (cross-wave landing guarantee - vmcnt is per-wave). Ledger: stage
// slot (e+2)&3 holds subtile e-2, last read 2 barriers ago; safe.
// swz_mode=1: panel-resident XCD mapping (A-panel group L2-resident).

__global__ __launch_bounds__(512, 2) void gemm256_kernel(
    const bf16_t* __restrict__ A, const bf16_t* __restrict__ Bt,
    void* __restrict__ Cp, const float* __restrict__ bias,
    float scale, int K,
    long lda, long ldb, long ldc,
    long strideA, long strideB, long strideC,
    int mtiles, int causal_skip, int causal_klimit, int c_f32, int swz_mode)
{
    __shared__ __align__(16) bf16_t As[4][256 * 32];
    __shared__ __align__(16) bf16_t Bs[4][256 * 32];

    int nwg = gridDim.x;
    int bid = blockIdx.x;
    int bm_t, bn_t;
    if (swz_mode == 1 && (mtiles & 7) == 0 && (nwg & 7) == 0) {
        int xcd = bid & 7;
        int l   = bid >> 3;          // local index within this XCD's chunk
        int mpx = mtiles >> 3;       // A-panels owned per XCD
        bm_t = xcd * mpx + (l % mpx);   // bm fast: A group L2-resident
        bn_t = l / mpx;                 // bn slow: B-panels stream 1-at-a-time
    } else {
        int swz = (bid & 7) * (nwg >> 3) + (bid >> 3);
        bm_t = swz % mtiles; bn_t = swz / mtiles;
    }
    if (causal_skip && bn_t > bm_t) return;   // uniform across block
    long bm0 = (long)bm_t * 256, bn0 = (long)bn_t * 256;

    int b = blockIdx.z;
    const char* Ab = (const char*)(A + (long)b * strideA + bm0 * lda);
    const char* Bb = (const char*)(Bt + (long)b * strideB + bn0 * ldb);
    long ldab = lda * 2, ldbb = ldb * 2;

    int tid = threadIdx.x, wave = tid >> 6, lane = tid & 63;
    int wm = wave >> 2, wn = wave & 3;
    int lr = lane & 15, kc = lane >> 4;

    int Kend = K;
    if (causal_klimit) { long kl = bm0 + 256; Kend = (kl < (long)K) ? (int)kl : K; }
    int NT = Kend >> 5;        // BK=32 subtiles (always even, >= 8 here)

    // ---- staging geometry: half-subtile = 128 rows x 64B; one gld_lds = 1KB/wave
    int offw = wave * 1024 + lane * 16;     // byte pos within 8KB half
    int rih  = offw >> 6;                   // row in half (0..127)
    long colswz = (long)(((lane & 3) ^ ((rih >> 1) & 3)) << 4);  // inverse-swizzled source slot
    long rowbA0 = (long)rih * ldab, rowbA1 = (long)(rih + 128) * ldab;
    long rowbB0 = (long)rih * ldbb, rowbB1 = (long)(rih + 128) * ldbb;
    int ldsoff = wave * 1024;

    auto STAGE_A = [&](int t, int slot) {   // both row-halves of A subtile t
        gld_lds16(Ab + rowbA0 + (long)t * 64 + colswz, (char*)As + slot * 16384 + ldsoff);
        gld_lds16(Ab + rowbA1 + (long)t * 64 + colswz, (char*)As + slot * 16384 + 8192 + ldsoff);
    };
    auto STAGE_B = [&](int t, int slot) {
        gld_lds16(Bb + rowbB0 + (long)t * 64 + colswz, (char*)Bs + slot * 16384 + ldsoff);
        gld_lds16(Bb + rowbB1 + (long)t * 64 + colswz, (char*)Bs + slot * 16384 + 8192 + ldsoff);
    };

    // ---- fragment read byte-offsets (swizzled), loop-invariant
    int aoff[8], boff[4];
#pragma unroll
    for (int m = 0; m < 8; ++m) {
        int row = wm * 128 + m * 16 + lr;
        aoff[m] = (row * 64 + kc * 16) ^ (((row >> 1) & 3) << 4);
    }
#pragma unroll
    for (int n = 0; n < 4; ++n) {
        int row = wn * 64 + n * 16 + lr;
        boff[n] = (row * 64 + kc * 16) ^ (((row >> 1) & 3) << 4);
    }

    f32x4 acc[8][4];
#pragma unroll
    for (int m = 0; m < 8; ++m)
#pragma unroll
        for (int n = 0; n < 4; ++n) acc[m][n] = (f32x4){0.f, 0.f, 0.f, 0.f};

    // ---- prologue: subtiles 0,1 staged (8 calls); wait subtile 0 (4 in flight)
    STAGE_A(0, 0); STAGE_B(0, 0);
    STAGE_A(1, 1); STAGE_B(1, 1);
    asm volatile("s_waitcnt vmcnt(4)" ::: "memory");
    __builtin_amdgcn_s_barrier();

    int NI = NT >> 1;
    for (int u = 0; u < NI; ++u) {
        int e = 2 * u, o = e + 1;
        int se = e & 3, so = o & 3;
        int t2 = (e + 2 < NT) ? e + 2 : NT - 1;  int s2 = (e + 2) & 3;
        int t3 = (o + 2 < NT) ? o + 2 : NT - 1;  int s3 = (o + 2) & 3;
        const char* AcE = (const char*)As + se * 16384;
        const char* BcE = (const char*)Bs + se * 16384;
        const char* AcO = (const char*)As + so * 16384;
        const char* BcO = (const char*)Bs + so * 16384;

        bf16x8 a0[4], a1[4], bf[4];

        // ---------- ph0: subtile e, Mlo
#pragma unroll
        for (int m = 0; m < 4; ++m) a0[m] = *(const bf16x8*)(AcE + aoff[m]);
#pragma unroll
        for (int n = 0; n < 4; ++n) bf[n] = *(const bf16x8*)(BcE + boff[n]);
        STAGE_A(t2, s2);
        __builtin_amdgcn_sched_barrier(0);
        __builtin_amdgcn_s_setprio(1);
#pragma unroll
        for (int m = 0; m < 4; ++m)
#pragma unroll
            for (int n = 0; n < 4; ++n)
                acc[m][n] = __builtin_amdgcn_mfma_f32_16x16x32_bf16(a0[m], bf[n], acc[m][n], 0, 0, 0);
        __builtin_amdgcn_s_setprio(0);
        __builtin_amdgcn_s_barrier();

        // ---------- ph1: subtile e, Mhi
#pragma unroll
        for (int m = 0; m < 4; ++m) a1[m] = *(const bf16x8*)(AcE + aoff[m + 4]);
        STAGE_B(t2, s2);
        __builtin_amdgcn_sched_barrier(0);
        __builtin_amdgcn_s_setprio(1);
#pragma unroll
        for (int m = 0; m < 4; ++m)
#pragma unroll
            for (int n = 0; n < 4; ++n)
                acc[m + 4][n] = __builtin_amdgcn_mfma_f32_16x16x32_bf16(a1[m], bf[n], acc[m + 4][n], 0, 0, 0);
        __builtin_amdgcn_s_setprio(0);
        asm volatile("s_waitcnt vmcnt(4)" ::: "memory");   // subtile o landed (A/B t2 in flight)
        __builtin_amdgcn_s_barrier();

        // ---------- ph2: subtile o, Mlo
#pragma unroll
        for (int m = 0; m < 4; ++m) a0[m] = *(const bf16x8*)(AcO + aoff[m]);
#pragma unroll
        for (int n = 0; n < 4; ++n) bf[n] = *(const bf16x8*)(BcO + boff[n]);
        STAGE_A(t3, s3);
        __builtin_amdgcn_sched_barrier(0);
        __builtin_amdgcn_s_setprio(1);
#pragma unroll
        for (int m = 0; m < 4; ++m)
#pragma unroll
            for (int n = 0; n < 4; ++n)
                acc[m][n] = __builtin_amdgcn_mfma_f32_16x16x32_bf16(a0[m], bf[n], acc[m][n], 0, 0, 0);
        __builtin_amdgcn_s_setprio(0);
        __builtin_amdgcn_s_barrier();

        // ---------- ph3: subtile o, Mhi
#pragma unroll
        for (int m = 0; m < 4; ++m) a1[m] = *(const bf16x8*)(AcO + aoff[m + 4]);
        STAGE_B(t3, s3);
        __builtin_amdgcn_sched_barrier(0);
        __builtin_amdgcn_s_setprio(1);
#pragma unroll
        for (int m = 0; m < 4; ++m)
#pragma unroll
            for (int n = 0; n < 4; ++n)
                acc[m + 4][n] = __builtin_amdgcn_mfma_f32_16x16x32_bf16(a1[m], bf[n], acc[m + 4][n], 0, 0, 0);
        __builtin_amdgcn_s_setprio(0);
        asm volatile("s_waitcnt vmcnt(4)" ::: "memory");   // subtile e+2 landed (A/B t3 in flight)
        __builtin_amdgcn_s_barrier();
    }

    asm volatile("s_waitcnt vmcnt(0)" ::: "memory");

    // ---- epilogue: D[row=(lane>>4)*4+r][col=lane&15] per 16x16 fragment
#pragma unroll
    for (int m = 0; m < 8; ++m) {
        long row = bm0 + wm * 128 + m * 16 + kc * 4;
#pragma unroll
        for (int n = 0; n < 4; ++n) {
            long col = bn0 + wn * 64 + n * 16 + lr;
            float bv = bias ? bias[col] : 0.f;
            if (c_f32) {
                float* Crow = (float*)Cp + (long)b * strideC;
#pragma unroll
                for (int r = 0; r < 4; ++r)
                    Crow[(row + r) * ldc + col] = acc[m][n][r] * scale + bv;
            } else {
                bf16_t* Crow = (bf16_t*)Cp + (long)b * strideC;
#pragma unroll
                for (int r = 0; r < 4; ++r)
                    Crow[(row + r) * ldc + col] = __float2bfloat16(acc[m][n][r] * scale + bv);
            }
        }
    }
}

// ---------------------------------------------------------------- causal softmax (in-place, bf16)
// Traffic-trimmed: skip loads where s0 > t, skip stores at cols >= klim
// (PV's causal K-limit means they are never read).

__global__ __launch_bounds__(256) void softmax_causal_kernel(bf16_t* S, int T) {
    int t = blockIdx.x;
    bf16_t* row = S + ((long)blockIdx.y * T + t) * (long)T;
    int tid = threadIdx.x;
    int s0 = tid * 8;
    int klim = ((t >> 8) + 1) << 8;

    u16x8 raw = {};
    if (s0 <= t) raw = *reinterpret_cast<const u16x8*>(&row[s0]);
    float v[8];
#pragma unroll
    for (int j = 0; j < 8; ++j) v[j] = __uint_as_float(((unsigned)raw[j]) << 16);

    float m = -1e30f;
#pragma unroll
    for (int j = 0; j < 8; ++j)
        if (s0 + j <= t) m = fmaxf(m, v[j]);

    __shared__ float red[8];
#pragma unroll
    for (int o = 32; o; o >>= 1) m = fmaxf(m, __shfl_xor(m, o, 64));
    if ((tid & 63) == 0) red[tid >> 6] = m;
    __syncthreads();
    m = fmaxf(fmaxf(red[0], red[1]), fmaxf(red[2], red[3]));
    __syncthreads();

    float e[8];
    float sum = 0.f;
#pragma unroll
    for (int j = 0; j < 8; ++j) {
        e[j] = (s0 + j <= t) ? __expf(v[j] - m) : 0.f;
        sum += e[j];
    }
#pragma unroll
    for (int o = 32; o; o >>= 1) sum += __shfl_xor(sum, o, 64);
    if ((tid & 63) == 0) red[tid >> 6] = sum;
    __syncthreads();
    sum = red[0] + red[1] + red[2] + red[3];
    float inv = 1.f / sum;

    if (s0 < klim) {
        u16x8 outp;
#pragma unroll
        for (int j = 0; j < 8; ++j) outp[j] = bf16_bits(e[j] * inv);
        *reinterpret_cast<u16x8*>(&row[s0]) = outp;
    }
}

// ---------------------------------------------------------------- launch

extern "C" void kernel_launch(void* const* d_in, const int* in_sizes, int n_in,
                              void* d_out, int out_size, void* d_ws, size_t ws_size,
                              hipStream_t stream) {
    const int B = 8, T = 2048, C = 1024;
    const int M = B * T;            // 16384
    const int N3 = 3 * C;           // 3072

    const float* x      = (const float*)d_in[0];
    const float* w_attn = (const float*)d_in[1];
    const float* b_attn = (const float*)d_in[2];
    const float* w_proj = (const float*)d_in[3];
    const float* b_proj = (const float*)d_in[4];
    float* out = (float*)d_out;     // reference output dtype is fp32

    char* ws = (char*)d_ws;

    // ---- adaptive workspace tiering ----
    const size_t BASE_FULL = 142606336ull;   // weights + qkv + xb/O
    const size_t PER_B     = 12582912ull;    // vT_b + S_b
    long NB = 0;
    if (ws_size >= BASE_FULL + PER_B) {
        NB = (long)((ws_size - BASE_FULL) / PER_B);
        if (NB > 8) NB = 8;
    }

    if (NB >= 1) {
        // ---------------- chunked path
        bf16_t* waT = (bf16_t*)(ws);                    // [3C, C]   6.3 MB
        bf16_t* wpT = (bf16_t*)(ws + 6291456);          // [C, C]    2.1 MB
        bf16_t* qkv = (bf16_t*)(ws + 8388608);          // [M, 3C] 100.7 MB
        bf16_t* xbO = (bf16_t*)(ws + 109051904);        // [M, C]   33.5 MB (xb, then O)
        bf16_t* vT  = (bf16_t*)(ws + 142606336);        // [NB, C, T]
        bf16_t* S   = (bf16_t*)(ws + 142606336 + (size_t)NB * 4194304); // [NB, T, T]

        cvt_f32_bf16_kernel<<<2048, 256, 0, stream>>>(x, xbO, (long)M * C / 4);

        transpose_f32_bf16_kernel<<<dim3(N3 / 32, C / 32, 1), dim3(32, 8), 0, stream>>>(
            w_attn, waT, N3, C);
        transpose_f32_bf16_kernel<<<dim3(C / 32, C / 32, 1), dim3(32, 8), 0, stream>>>(
            w_proj, wpT, C, C);

        // qkv = xb @ w_attn + b_attn   (panel-resident swizzle)
        gemm256_kernel<<<dim3((M / 256) * (N3 / 256), 1, 1), 512, 0, stream>>>(
            xbO, waT, qkv, b_attn, 1.0f, C,
            C, C, N3, 0, 0, 0, M / 256, 0, 0, 0, 1);

        for (long b0 = 0; b0 < B; b0 += NB) {
            long nb = (B - b0 < NB) ? (B - b0) : NB;
            const bf16_t* qkv_c = qkv + b0 * (long)T * N3;
            bf16_t* O_c = xbO + b0 * (long)T * C;

            transpose_bf16_kernel<<<dim3(C / 32, T / 32, nb), dim3(32, 8), 0, stream>>>(
                qkv_c + 2 * C, vT, N3, T, (long)T * N3, (long)C * T);

            // S = (Q K^T)/sqrt(C), causal block-skip (balanced old swizzle)
            gemm256_kernel<<<dim3((T / 256) * (T / 256), 1, nb), 512, 0, stream>>>(
                qkv_c, qkv_c + C, S, nullptr, 0.03125f, C,
                N3, N3, T, (long)T * N3, (long)T * N3, (long)T * T, T / 256, 1, 0, 0, 0);

            softmax_causal_kernel<<<dim3(T, nb), 256, 0, stream>>>(S, T);

            // O = P @ V, causal K-limit (balanced old swizzle)
            gemm256_kernel<<<dim3((T / 256) * (C / 256), 1, nb), 512, 0, stream>>>(
                S, vT, O_c, nullptr, 1.0f, T,
                T, T, C, (long)T * T, (long)C * T, (long)T * C, T / 256, 0, 1, 0, 0);
        }

        // out = O @ w_proj + b_proj   (fp32 store, panel-resident swizzle)
        gemm256_kernel<<<dim3((M / 256) * (C / 256), 1, 1), 512, 0, stream>>>(
            xbO, wpT, out, b_proj, 1.0f, C,
            C, C, C, 0, 0, 0, M / 256, 0, 0, 1, 1);
    } else {
        // ---------------- per-batch fallback (36 MB total)
        bf16_t* waT  = (bf16_t*)(ws);                   // [3C, C]   6.3 MB
        bf16_t* wpT  = (bf16_t*)(ws + 6291456);         // [C, C]    2.1 MB
        bf16_t* xbO  = (bf16_t*)(ws + 8388608);         // [T, C]    4.2 MB
        bf16_t* qkvb = (bf16_t*)(ws + 12582912);        // [T, 3C]  12.6 MB
        bf16_t* vTb  = (bf16_t*)(ws + 25165824);        // [C, T]    4.2 MB
        bf16_t* Sb   = (bf16_t*)(ws + 29360128);        // [T, T]    8.4 MB

        transpose_f32_bf16_kernel<<<dim3(N3 / 32, C / 32, 1), dim3(32, 8), 0, stream>>>(
            w_attn, waT, N3, C);
        transpose_f32_bf16_kernel<<<dim3(C / 32, C / 32, 1), dim3(32, 8), 0, stream>>>(
            w_proj, wpT, C, C);

        for (int b = 0; b < B; ++b) {
            const float* x_b = x + (long)b * T * C;
            float* out_b = out + (long)b * T * C;

            cvt_f32_bf16_kernel<<<1024, 256, 0, stream>>>(x_b, xbO, (long)T * C / 4);

            gemm256_kernel<<<dim3((T / 256) * (N3 / 256), 1, 1), 512, 0, stream>>>(
                xbO, waT, qkvb, b_attn, 1.0f, C,
                C, C, N3, 0, 0, 0, T / 256, 0, 0, 0, 1);

            transpose_bf16_kernel<<<dim3(C / 32, T / 32, 1), dim3(32, 8), 0, stream>>>(
                qkvb + 2 * C, vTb, N3, T, 0, 0);

            gemm256_kernel<<<dim3((T / 256) * (T / 256), 1, 1), 512, 0, stream>>>(
                qkvb, qkvb + C, Sb, nullptr, 0.03125f, C,
                N3, N3, T, 0, 0, 0, T / 256, 1, 0, 0, 0);

            softmax_causal_kernel<<<dim3(T, 1), 256, 0, stream>>>(Sb, T);

            gemm256_kernel<<<dim3((T / 256) * (C / 256), 1, 1), 512, 0, stream>>>(
                Sb, vTb, xbO, nullptr, 1.0f, T,
                T, T, C, 0, 0, 0, T / 256, 0, 1, 0, 0);

            gemm256_kernel<<<dim3((T / 256) * (C / 256), 1, 1), 512, 0, stream>>>(
                xbO, wpT, out_b, b_proj, 1.0f, C,
                C, C, C, 0, 0, 0, T / 256, 0, 0, 1, 1);
        }
    }
}

// Round 12
// 378.358 us; speedup vs baseline: 1.0547x; 1.0547x over previous
//
#include <hip/hip_runtime.h>
#include <hip/hip_bf16.h>

typedef __hip_bfloat16 bf16_t;
typedef __attribute__((ext_vector_type(8))) __bf16 bf16x8;
typedef __attribute__((ext_vector_type(4))) float f32x4;
typedef __attribute__((ext_vector_type(8))) unsigned short u16x8;

// ---------------------------------------------------------------- helpers

__device__ __forceinline__ void gld_lds16(const void* g, void* l) {
    __builtin_amdgcn_global_load_lds(
        (const __attribute__((address_space(1))) unsigned int*)g,
        (__attribute__((address_space(3))) unsigned int*)l,
        16, 0, 0);
}

__device__ __forceinline__ unsigned short bf16_bits(float x) {
    bf16_t b = __float2bfloat16(x);
    return *reinterpret_cast<unsigned short*>(&b);
}

// ---------------------------------------------------------------- convert x -> bf16

__global__ __launch_bounds__(256) void cvt_f32_bf16_kernel(
    const float* __restrict__ in, bf16_t* __restrict__ out, long n4) {
    long stride = (long)gridDim.x * blockDim.x;
    for (long i = (long)blockIdx.x * blockDim.x + threadIdx.x; i < n4; i += stride) {
        float4 v = reinterpret_cast<const float4*>(in)[i];
        ushort4 o;
        o.x = bf16_bits(v.x);
        o.y = bf16_bits(v.y);
        o.z = bf16_bits(v.z);
        o.w = bf16_bits(v.w);
        reinterpret_cast<ushort4*>(out)[i] = o;
    }
}

// ---------------------------------------------------------------- transposes

__global__ __launch_bounds__(256) void transpose_f32_bf16_kernel(
    const float* __restrict__ in, bf16_t* __restrict__ out, long ldin, long ldout) {
    __shared__ float tile[32][33];
    int c0 = blockIdx.x * 32, r0 = blockIdx.y * 32;
    int x = threadIdx.x;
#pragma unroll
    for (int yy = 0; yy < 4; ++yy) {
        int y = threadIdx.y + yy * 8;
        tile[y][x] = in[(long)(r0 + y) * ldin + c0 + x];
    }
    __syncthreads();
#pragma unroll
    for (int yy = 0; yy < 4; ++yy) {
        int y = threadIdx.y + yy * 8;
        out[(long)(c0 + y) * ldout + r0 + x] = __float2bfloat16(tile[x][y]);
    }
}

__global__ __launch_bounds__(256) void transpose_bf16_kernel(
    const bf16_t* __restrict__ in, bf16_t* __restrict__ out,
    long ldin, long ldout, long sIn, long sOut) {
    __shared__ bf16_t tile[32][33];
    in  += (long)blockIdx.z * sIn;
    out += (long)blockIdx.z * sOut;
    int c0 = blockIdx.x * 32, r0 = blockIdx.y * 32;
    int x = threadIdx.x;
#pragma unroll
    for (int yy = 0; yy < 4; ++yy) {
        int y = threadIdx.y + yy * 8;
        tile[y][x] = in[(long)(r0 + y) * ldin + c0 + x];
    }
    __syncthreads();
#pragma unroll
    for (int yy = 0; yy < 4; ++yy) {
        int y = threadIdx.y + yy * 8;
        out[(long)(c0 + y) * ldout + r0 + x] = tile[x][y];
    }
}

// ---------------------------------------------------------------- 256x256 8-wave GEMM, m201-geometry port
// C[M,N] = scale*(A[M,K] @ Bt[N,K]^T) + bias[N]
// 512 threads = 8 waves (2M x 4N); wave tile 128x64; BK=64 K-steps.
// LDS: 2 dbuf x (A[256][64] + B[256][64]) bf16 = 128 KiB; chunk^=(row&7)
// XOR swizzle both sides (reads <=2-way aliased = free).
// 4 phases per K-step, 16 MFMA each (wave-tile quadrants):
//  ph1: read A-qlo(8)+B-lo(4) | stage A-Q1,Q3(t+1) | bar,lgkm0 | MFMA m0-3 x n0-1 | bar
//  ph2: read B-hi(4)          | stage A-Q0,Q2(t+2) | bar,lgkm0 | MFMA m0-3 x n2-3 | bar
//  ph3: read A-qhi(8)         | stage B-Q0,Q1(t+2) | bar,lgkm0 | MFMA m4-7 x n2-3 | bar
//  ph4: (no reads)            | stage B-Q2,Q3(t+2) |           | MFMA m4-7 x n0-1 | vmcnt(6) bar
// Liveness ledger: A rows {0-63,128-191} die ph1, {64-127,192-255} die ph3;
// B quarters die ph2. Every staged slot is >=1 barrier past its last read.
// vmcnt(6) leaves exactly ph2-ph4's 6 loads in flight and retires ALL of
// step t+1 before the barrier opening it (vmcnt is per-wave; barrier gives
// the cross-wave guarantee). Never drained in-loop.
// swz_mode=1: panel-resident XCD mapping (A-panel group L2-resident).

__global__ __launch_bounds__(512, 2) void gemm256_kernel(
    const bf16_t* __restrict__ A, const bf16_t* __restrict__ Bt,
    void* __restrict__ Cp, const float* __restrict__ bias,
    float scale, int K,
    long lda, long ldb, long ldc,
    long strideA, long strideB, long strideC,
    int mtiles, int causal_skip, int causal_klimit, int c_f32, int swz_mode)
{
    __shared__ __align__(16) bf16_t As[2][256 * 64];
    __shared__ __align__(16) bf16_t Bs[2][256 * 64];

    int nwg = gridDim.x;
    int bid = blockIdx.x;
    int bm_t, bn_t;
    if (swz_mode == 1 && (mtiles & 7) == 0 && (nwg & 7) == 0) {
        int xcd = bid & 7;
        int l   = bid >> 3;
        int mpx = mtiles >> 3;
        bm_t = xcd * mpx + (l % mpx);   // bm fast: A group L2-resident
        bn_t = l / mpx;                 // bn slow: B-panels stream
    } else {
        int swz = (bid & 7) * (nwg >> 3) + (bid >> 3);
        bm_t = swz % mtiles; bn_t = swz / mtiles;
    }
    if (causal_skip && bn_t > bm_t) return;
    long bm0 = (long)bm_t * 256, bn0 = (long)bn_t * 256;

    int b = blockIdx.z;
    const char* Ab = (const char*)(A + (long)b * strideA + bm0 * lda);
    const char* Bb = (const char*)(Bt + (long)b * strideB + bn0 * ldb);
    long ldab = lda * 2, ldbb = ldb * 2;

    int tid = threadIdx.x, wave = tid >> 6, lane = tid & 63;
    int wm = wave >> 2, wn = wave & 3;
    int lr = lane & 15, kc = lane >> 4;

    int Kend = K;
    if (causal_klimit) { long kl = bm0 + 256; Kend = (kl < (long)K) ? (int)kl : K; }
    int NT = Kend >> 6;        // BK=64 K-steps (>= 4 for all shapes here)

    // ---- staging: one gld_lds/wave = 1KB = 8 rows x 128B; one STG call
    // (8 waves) covers a 64-row quarter. Source chunk inverse-swizzled.
    int rowst = wave * 8 + (lane >> 3);                    // row within quarter
    long cswz = (long)(((lane & 7) ^ (lane >> 3)) << 4);   // chunk ^ (row&7)
    int ldsoff = wave * 1024;

    auto STG_A = [&](int t, int q, int slot) {
        gld_lds16(Ab + (long)(q * 64 + rowst) * ldab + (long)t * 128 + cswz,
                  (char*)As + slot * 32768 + q * 8192 + ldsoff);
    };
    auto STG_B = [&](int t, int q, int slot) {
        gld_lds16(Bb + (long)(q * 64 + rowst) * ldbb + (long)t * 128 + cswz,
                  (char*)Bs + slot * 32768 + q * 8192 + ldsoff);
    };

    // ---- fragment addresses: row*128 + (kh*64 + kc*16) ^ ((lr&7)<<4)
    int xk0 = (kc * 16) ^ ((lr & 7) << 4);
    int xk1 = (64 + kc * 16) ^ ((lr & 7) << 4);
    int arow[8], brow[4];
#pragma unroll
    for (int m = 0; m < 8; ++m) arow[m] = (wm * 128 + m * 16 + lr) * 128;
#pragma unroll
    for (int n = 0; n < 4; ++n) brow[n] = (wn * 64 + n * 16 + lr) * 128;

    f32x4 acc[8][4];
#pragma unroll
    for (int m = 0; m < 8; ++m)
#pragma unroll
        for (int n = 0; n < 4; ++n) acc[m][n] = (f32x4){0.f, 0.f, 0.f, 0.f};

    // ---- prologue: t0 all 8 quarters; t1 all except A-Q1,Q3 (staged ph1(0))
    STG_A(0, 0, 0); STG_A(0, 1, 0); STG_A(0, 2, 0); STG_A(0, 3, 0);
    STG_B(0, 0, 0); STG_B(0, 1, 0); STG_B(0, 2, 0); STG_B(0, 3, 0);
    STG_A(1, 0, 1); STG_A(1, 2, 1);
    STG_B(1, 0, 1); STG_B(1, 1, 1); STG_B(1, 2, 1); STG_B(1, 3, 1);
    asm volatile("s_waitcnt vmcnt(6)" ::: "memory");   // t0 landed; t1's 6 in flight
    __builtin_amdgcn_s_barrier();

    bf16x8 a[4][2], bl[2][2], bh[2][2];

    for (int t = 0; t < NT; ++t) {
        int s  = t & 1, sn = s ^ 1;
        int tn = (t + 1 < NT) ? t + 1 : NT - 1;
        int t2 = (t + 2 < NT) ? t + 2 : NT - 1;
        const char* Ac = (const char*)As + s * 32768;
        const char* Bc = (const char*)Bs + s * 32768;

        // -------- ph1: A-quad-lo + B-lo reads; stage A-Q1,Q3(t+1)
#pragma unroll
        for (int m = 0; m < 4; ++m) {
            a[m][0] = *(const bf16x8*)(Ac + arow[m] + xk0);
            a[m][1] = *(const bf16x8*)(Ac + arow[m] + xk1);
        }
#pragma unroll
        for (int n = 0; n < 2; ++n) {
            bl[n][0] = *(const bf16x8*)(Bc + brow[n] + xk0);
            bl[n][1] = *(const bf16x8*)(Bc + brow[n] + xk1);
        }
        STG_A(tn, 1, sn); STG_A(tn, 3, sn);
        __builtin_amdgcn_sched_barrier(0);
        __builtin_amdgcn_s_barrier();
        asm volatile("s_waitcnt lgkmcnt(0)" ::: "memory");
        __builtin_amdgcn_sched_barrier(0);
        __builtin_amdgcn_s_setprio(1);
#pragma unroll
        for (int m = 0; m < 4; ++m)
#pragma unroll
            for (int n = 0; n < 2; ++n) {
                acc[m][n] = __builtin_amdgcn_mfma_f32_16x16x32_bf16(a[m][0], bl[n][0], acc[m][n], 0, 0, 0);
                acc[m][n] = __builtin_amdgcn_mfma_f32_16x16x32_bf16(a[m][1], bl[n][1], acc[m][n], 0, 0, 0);
            }
        __builtin_amdgcn_s_setprio(0);
        __builtin_amdgcn_s_barrier();

        // -------- ph2: B-hi reads; stage A-Q0,Q2(t+2)
#pragma unroll
        for (int n = 0; n < 2; ++n) {
            bh[n][0] = *(const bf16x8*)(Bc + brow[n + 2] + xk0);
            bh[n][1] = *(const bf16x8*)(Bc + brow[n + 2] + xk1);
        }
        STG_A(t2, 0, s); STG_A(t2, 2, s);
        __builtin_amdgcn_sched_barrier(0);
        __builtin_amdgcn_s_barrier();
        asm volatile("s_waitcnt lgkmcnt(0)" ::: "memory");
        __builtin_amdgcn_sched_barrier(0);
        __builtin_amdgcn_s_setprio(1);
#pragma unroll
        for (int m = 0; m < 4; ++m)
#pragma unroll
            for (int n = 0; n < 2; ++n) {
                acc[m][n + 2] = __builtin_amdgcn_mfma_f32_16x16x32_bf16(a[m][0], bh[n][0], acc[m][n + 2], 0, 0, 0);
                acc[m][n + 2] = __builtin_amdgcn_mfma_f32_16x16x32_bf16(a[m][1], bh[n][1], acc[m][n + 2], 0, 0, 0);
            }
        __builtin_amdgcn_s_setprio(0);
        __builtin_amdgcn_s_barrier();

        // -------- ph3: A-quad-hi reads; stage B-Q0,Q1(t+2)
#pragma unroll
        for (int m = 0; m < 4; ++m) {
            a[m][0] = *(const bf16x8*)(Ac + arow[m + 4] + xk0);
            a[m][1] = *(const bf16x8*)(Ac + arow[m + 4] + xk1);
        }
        STG_B(t2, 0, s); STG_B(t2, 1, s);
        __builtin_amdgcn_sched_barrier(0);
        __builtin_amdgcn_s_barrier();
        asm volatile("s_waitcnt lgkmcnt(0)" ::: "memory");
        __builtin_amdgcn_sched_barrier(0);
        __builtin_amdgcn_s_setprio(1);
#pragma unroll
        for (int m = 0; m < 4; ++m)
#pragma unroll
            for (int n = 0; n < 2; ++n) {
                acc[m + 4][n + 2] = __builtin_amdgcn_mfma_f32_16x16x32_bf16(a[m][0], bh[n][0], acc[m + 4][n + 2], 0, 0, 0);
                acc[m + 4][n + 2] = __builtin_amdgcn_mfma_f32_16x16x32_bf16(a[m][1], bh[n][1], acc[m + 4][n + 2], 0, 0, 0);
            }
        __builtin_amdgcn_s_setprio(0);
        __builtin_amdgcn_s_barrier();

        // -------- ph4: no reads; stage B-Q2,Q3(t+2); vmcnt(6) once per K-step
        STG_B(t2, 2, s); STG_B(t2, 3, s);
        __builtin_amdgcn_sched_barrier(0);
        __builtin_amdgcn_s_setprio(1);
#pragma unroll
        for (int m = 0; m < 4; ++m)
#pragma unroll
            for (int n = 0; n < 2; ++n) {
                acc[m + 4][n] = __builtin_amdgcn_mfma_f32_16x16x32_bf16(a[m][0], bl[n][0], acc[m + 4][n], 0, 0, 0);
                acc[m + 4][n] = __builtin_amdgcn_mfma_f32_16x16x32_bf16(a[m][1], bl[n][1], acc[m + 4][n], 0, 0, 0);
            }
        __builtin_amdgcn_s_setprio(0);
        asm volatile("s_waitcnt vmcnt(6)" ::: "memory");   // all of t+1 landed
        __builtin_amdgcn_s_barrier();
    }

    asm volatile("s_waitcnt vmcnt(0)" ::: "memory");

    // ---- epilogue: D[row=(lane>>4)*4+r][col=lane&15] per 16x16 fragment
#pragma unroll
    for (int m = 0; m < 8; ++m) {
        long row = bm0 + wm * 128 + m * 16 + kc * 4;
#pragma unroll
        for (int n = 0; n < 4; ++n) {
            long col = bn0 + wn * 64 + n * 16 + lr;
            float bv = bias ? bias[col] : 0.f;
            if (c_f32) {
                float* Crow = (float*)Cp + (long)b * strideC;
#pragma unroll
                for (int r = 0; r < 4; ++r)
                    Crow[(row + r) * ldc + col] = acc[m][n][r] * scale + bv;
            } else {
                bf16_t* Crow = (bf16_t*)Cp + (long)b * strideC;
#pragma unroll
                for (int r = 0; r < 4; ++r)
                    Crow[(row + r) * ldc + col] = __float2bfloat16(acc[m][n][r] * scale + bv);
            }
        }
    }
}

// ---------------------------------------------------------------- causal softmax (in-place, bf16)

__global__ __launch_bounds__(256) void softmax_causal_kernel(bf16_t* S, int T) {
    int t = blockIdx.x;
    bf16_t* row = S + ((long)blockIdx.y * T + t) * (long)T;
    int tid = threadIdx.x;
    int s0 = tid * 8;
    int klim = ((t >> 8) + 1) << 8;

    u16x8 raw = {};
    if (s0 <= t) raw = *reinterpret_cast<const u16x8*>(&row[s0]);
    float v[8];
#pragma unroll
    for (int j = 0; j < 8; ++j) v[j] = __uint_as_float(((unsigned)raw[j]) << 16);

    float m = -1e30f;
#pragma unroll
    for (int j = 0; j < 8; ++j)
        if (s0 + j <= t) m = fmaxf(m, v[j]);

    __shared__ float red[8];
#pragma unroll
    for (int o = 32; o; o >>= 1) m = fmaxf(m, __shfl_xor(m, o, 64));
    if ((tid & 63) == 0) red[tid >> 6] = m;
    __syncthreads();
    m = fmaxf(fmaxf(red[0], red[1]), fmaxf(red[2], red[3]));
    __syncthreads();

    float e[8];
    float sum = 0.f;
#pragma unroll
    for (int j = 0; j < 8; ++j) {
        e[j] = (s0 + j <= t) ? __expf(v[j] - m) : 0.f;
        sum += e[j];
    }
#pragma unroll
    for (int o = 32; o; o >>= 1) sum += __shfl_xor(sum, o, 64);
    if ((tid & 63) == 0) red[tid >> 6] = sum;
    __syncthreads();
    sum = red[0] + red[1] + red[2] + red[3];
    float inv = 1.f / sum;

    if (s0 < klim) {
        u16x8 outp;
#pragma unroll
        for (int j = 0; j < 8; ++j) outp[j] = bf16_bits(e[j] * inv);
        *reinterpret_cast<u16x8*>(&row[s0]) = outp;
    }
}

// ---------------------------------------------------------------- launch

extern "C" void kernel_launch(void* const* d_in, const int* in_sizes, int n_in,
                              void* d_out, int out_size, void* d_ws, size_t ws_size,
                              hipStream_t stream) {
    const int B = 8, T = 2048, C = 1024;
    const int M = B * T;            // 16384
    const int N3 = 3 * C;           // 3072

    const float* x      = (const float*)d_in[0];
    const float* w_attn = (const float*)d_in[1];
    const float* b_attn = (const float*)d_in[2];
    const float* w_proj = (const float*)d_in[3];
    const float* b_proj = (const float*)d_in[4];
    float* out = (float*)d_out;     // reference output dtype is fp32

    char* ws = (char*)d_ws;

    // ---- adaptive workspace tiering ----
    const size_t BASE_FULL = 142606336ull;   // weights + qkv + xb/O
    const size_t PER_B     = 12582912ull;    // vT_b + S_b
    long NB = 0;
    if (ws_size >= BASE_FULL + PER_B) {
        NB = (long)((ws_size - BASE_FULL) / PER_B);
        if (NB > 8) NB = 8;
    }

    if (NB >= 1) {
        // ---------------- chunked path
        bf16_t* waT = (bf16_t*)(ws);                    // [3C, C]   6.3 MB
        bf16_t* wpT = (bf16_t*)(ws + 6291456);          // [C, C]    2.1 MB
        bf16_t* qkv = (bf16_t*)(ws + 8388608);          // [M, 3C] 100.7 MB
        bf16_t* xbO = (bf16_t*)(ws + 109051904);        // [M, C]   33.5 MB (xb, then O)
        bf16_t* vT  = (bf16_t*)(ws + 142606336);        // [NB, C, T]
        bf16_t* S   = (bf16_t*)(ws + 142606336 + (size_t)NB * 4194304); // [NB, T, T]

        cvt_f32_bf16_kernel<<<2048, 256, 0, stream>>>(x, xbO, (long)M * C / 4);

        transpose_f32_bf16_kernel<<<dim3(N3 / 32, C / 32, 1), dim3(32, 8), 0, stream>>>(
            w_attn, waT, N3, C);
        transpose_f32_bf16_kernel<<<dim3(C / 32, C / 32, 1), dim3(32, 8), 0, stream>>>(
            w_proj, wpT, C, C);

        // qkv = xb @ w_attn + b_attn   (panel-resident swizzle)
        gemm256_kernel<<<dim3((M / 256) * (N3 / 256), 1, 1), 512, 0, stream>>>(
            xbO, waT, qkv, b_attn, 1.0f, C,
            C, C, N3, 0, 0, 0, M / 256, 0, 0, 0, 1);

        for (long b0 = 0; b0 < B; b0 += NB) {
            long nb = (B - b0 < NB) ? (B - b0) : NB;
            const bf16_t* qkv_c = qkv + b0 * (long)T * N3;
            bf16_t* O_c = xbO + b0 * (long)T * C;

            transpose_bf16_kernel<<<dim3(C / 32, T / 32, nb), dim3(32, 8), 0, stream>>>(
                qkv_c + 2 * C, vT, N3, T, (long)T * N3, (long)C * T);

            // S = (Q K^T)/sqrt(C), causal block-skip (balanced swizzle)
            gemm256_kernel<<<dim3((T / 256) * (T / 256), 1, nb), 512, 0, stream>>>(
                qkv_c, qkv_c + C, S, nullptr, 0.03125f, C,
                N3, N3, T, (long)T * N3, (long)T * N3, (long)T * T, T / 256, 1, 0, 0, 0);

            softmax_causal_kernel<<<dim3(T, nb), 256, 0, stream>>>(S, T);

            // O = P @ V, causal K-limit (balanced swizzle)
            gemm256_kernel<<<dim3((T / 256) * (C / 256), 1, nb), 512, 0, stream>>>(
                S, vT, O_c, nullptr, 1.0f, T,
                T, T, C, (long)T * T, (long)C * T, (long)T * C, T / 256, 0, 1, 0, 0);
        }

        // out = O @ w_proj + b_proj   (fp32 store, panel-resident swizzle)
        gemm256_kernel<<<dim3((M / 256) * (C / 256), 1, 1), 512, 0, stream>>>(
            xbO, wpT, out, b_proj, 1.0f, C,
            C, C, C, 0, 0, 0, M / 256, 0, 0, 1, 1);
    } else {
        // ---------------- per-batch fallback (36 MB total)
        bf16_t* waT  = (bf16_t*)(ws);                   // [3C, C]   6.3 MB
        bf16_t* wpT  = (bf16_t*)(ws + 6291456);         // [C, C]    2.1 MB
        bf16_t* xbO  = (bf16_t*)(ws + 8388608);         // [T, C]    4.2 MB
        bf16_t* qkvb = (bf16_t*)(ws + 12582912);        // [T, 3C]  12.6 MB
        bf16_t* vTb  = (bf16_t*)(ws + 25165824);        // [C, T]    4.2 MB
        bf16_t* Sb   = (bf16_t*)(ws + 29360128);        // [T, T]    8.4 MB

        transpose_f32_bf16_kernel<<<dim3(N3 / 32, C / 32, 1), dim3(32, 8), 0, stream>>>(
            w_attn, waT, N3, C);
        transpose_f32_bf16_kernel<<<dim3(C / 32, C / 32, 1), dim3(32, 8), 0, stream>>>(
            w_proj, wpT, C, C);

        for (int b = 0; b < B; ++b) {
            const float* x_b = x + (long)b * T * C;
            float* out_b = out + (long)b * T * C;

            cvt_f32_bf16_kernel<<<1024, 256, 0, stream>>>(x_b, xbO, (long)T * C / 4);

            gemm256_kernel<<<dim3((T / 256) * (N3 / 256), 1, 1), 512, 0, stream>>>(
                xbO, waT, qkvb, b_attn, 1.0f, C,
                C, C, N3, 0, 0, 0, T / 256, 0, 0, 0, 1);

            transpose_bf16_kernel<<<dim3(C / 32, T / 32, 1), dim3(32, 8), 0, stream>>>(
                qkvb + 2 * C, vTb, N3, T, 0, 0);

            gemm256_kernel<<<dim3((T / 256) * (T / 256), 1, 1), 512, 0, stream>>>(
                qkvb, qkvb + C, Sb, nullptr, 0.03125f, C,
                N3, N3, T, 0, 0, 0, T / 256, 1, 0, 0, 0);

            softmax_causal_kernel<<<dim3(T, 1), 256, 0, stream>>>(Sb, T);

            gemm256_kernel<<<dim3((T / 256) * (C / 256), 1, 1), 512, 0, stream>>>(
                Sb, vTb, xbO, nullptr, 1.0f, T,
                T, T, C, 0, 0, 0, T / 256, 0, 1, 0, 0);

            gemm256_kernel<<<dim3((T / 256) * (C / 256), 1, 1), 512, 0, stream>>>(
                xbO, wpT, out_b, b_proj, 1.0f, C,
                C, C, C, 0, 0, 0, T / 256, 0, 0, 1, 1);
        }
    }
}

// Round 13
// 343.582 us; speedup vs baseline: 1.1615x; 1.1012x over previous
//
#include <hip/hip_runtime.h>
#include <hip/hip_bf16.h>

typedef __hip_bfloat16 bf16_t;
typedef __attribute__((ext_vector_type(8))) __bf16 bf16x8;
typedef __attribute__((ext_vector_type(4))) float f32x4;
typedef __attribute__((ext_vector_type(8))) unsigned short u16x8;

// ---------------------------------------------------------------- helpers

__device__ __forceinline__ void gld_lds16(const void* g, void* l) {
    // async global->LDS, 16B per lane. LDS dest is wave-uniform base + lane*16.
    __builtin_amdgcn_global_load_lds(
        (const __attribute__((address_space(1))) unsigned int*)g,
        (__attribute__((address_space(3))) unsigned int*)l,
        16, 0, 0);
}

__device__ __forceinline__ unsigned short bf16_bits(float x) {
    bf16_t b = __float2bfloat16(x);
    return *reinterpret_cast<unsigned short*>(&b);
}

// ---------------------------------------------------------------- convert x -> bf16

__global__ __launch_bounds__(256) void cvt_f32_bf16_kernel(
    const float* __restrict__ in, bf16_t* __restrict__ out, long n4) {
    long stride = (long)gridDim.x * blockDim.x;
    for (long i = (long)blockIdx.x * blockDim.x + threadIdx.x; i < n4; i += stride) {
        float4 v = reinterpret_cast<const float4*>(in)[i];
        ushort4 o;
        o.x = bf16_bits(v.x);
        o.y = bf16_bits(v.y);
        o.z = bf16_bits(v.z);
        o.w = bf16_bits(v.w);
        reinterpret_cast<ushort4*>(out)[i] = o;
    }
}

// ---------------------------------------------------------------- transposes

__global__ __launch_bounds__(256) void transpose_f32_bf16_kernel(
    const float* __restrict__ in, bf16_t* __restrict__ out, long ldin, long ldout) {
    __shared__ float tile[32][33];
    int c0 = blockIdx.x * 32, r0 = blockIdx.y * 32;
    int x = threadIdx.x;
#pragma unroll
    for (int yy = 0; yy < 4; ++yy) {
        int y = threadIdx.y + yy * 8;
        tile[y][x] = in[(long)(r0 + y) * ldin + c0 + x];
    }
    __syncthreads();
#pragma unroll
    for (int yy = 0; yy < 4; ++yy) {
        int y = threadIdx.y + yy * 8;
        out[(long)(c0 + y) * ldout + r0 + x] = __float2bfloat16(tile[x][y]);
    }
}

__global__ __launch_bounds__(256) void transpose_bf16_kernel(
    const bf16_t* __restrict__ in, bf16_t* __restrict__ out,
    long ldin, long ldout, long sIn, long sOut) {
    __shared__ bf16_t tile[32][33];
    in  += (long)blockIdx.z * sIn;
    out += (long)blockIdx.z * sOut;
    int c0 = blockIdx.x * 32, r0 = blockIdx.y * 32;
    int x = threadIdx.x;
#pragma unroll
    for (int yy = 0; yy < 4; ++yy) {
        int y = threadIdx.y + yy * 8;
        tile[y][x] = in[(long)(r0 + y) * ldin + c0 + x];
    }
    __syncthreads();
#pragma unroll
    for (int yy = 0; yy < 4; ++yy) {
        int y = threadIdx.y + yy * 8;
        out[(long)(c0 + y) * ldout + r0 + x] = tile[x][y];
    }
}

// ---------------------------------------------------------------- 256x256 8-wave GEMM, 1 barrier / K-tile
// (round-7/10 inner loop - best measured. Schedule variants r5/r6/r8/r11/r12
// all regressed; do not re-derive without new counter evidence.)
// swz_mode=1 (uniform-K GEMMs): panel-resident XCD mapping - xcd=bid&7 owns
//   mtiles/8 contiguous A-panels (bm fast -> ~4MB A group L2-resident).
//   Measured: qkv FETCH 202MB -> 74MB.
// swz_mode=0 (causal QK^T / K-limited PV): generic balanced swizzle.
// V-fusion: for output cols >= vsplit (qkv GEMM's V range), write ONLY the
//   transposed form to Vt[b][c][t] (fragment's 4 acc rows = 4 consecutive
//   tokens at one channel = one aligned 8B ushort4 store); skip the qkv copy.

__global__ __launch_bounds__(512, 2) void gemm256_kernel(
    const bf16_t* __restrict__ A, const bf16_t* __restrict__ Bt,
    void* __restrict__ Cp, const float* __restrict__ bias,
    float scale, int K,
    long lda, long ldb, long ldc,
    long strideA, long strideB, long strideC,
    int mtiles, int causal_skip, int causal_klimit, int c_f32, int swz_mode,
    bf16_t* __restrict__ Vt, int vsplit)
{
    __shared__ __align__(16) bf16_t As[3][256 * 32];
    __shared__ __align__(16) bf16_t Bs[3][256 * 32];

    int nwg = gridDim.x;
    int bid = blockIdx.x;
    int bm_t, bn_t;
    if (swz_mode == 1 && (mtiles & 7) == 0 && (nwg & 7) == 0) {
        int xcd = bid & 7;
        int l   = bid >> 3;          // local index within this XCD's chunk
        int mpx = mtiles >> 3;       // A-panels owned per XCD
        bm_t = xcd * mpx + (l % mpx);   // bm fast: A group L2-resident
        bn_t = l / mpx;                 // bn slow: B-panels stream 1-at-a-time
    } else {
        int swz = (bid & 7) * (nwg >> 3) + (bid >> 3);
        bm_t = swz % mtiles; bn_t = swz / mtiles;
    }
    if (causal_skip && bn_t > bm_t) return;   // uniform across block
    long bm0 = (long)bm_t * 256, bn0 = (long)bn_t * 256;

    int b = blockIdx.z;
    const char* Ab = (const char*)(A + (long)b * strideA + bm0 * lda);
    const char* Bb = (const char*)(Bt + (long)b * strideB + bn0 * ldb);
    long ldab = lda * 2, ldbb = ldb * 2;

    int tid = threadIdx.x, wave = tid >> 6, lane = tid & 63;
    int wm = wave >> 2, wn = wave & 3;
    int lr = lane & 15, kc = lane >> 4;

    int Kend = K;
    if (causal_klimit) { long kl = bm0 + 256; Kend = (kl < (long)K) ? (int)kl : K; }
    int NT = Kend >> 5;        // K-tiles of 32 (always >= 8 here)

    // ---- staging geometry: half-tile = 128 rows x 64B; one gld_lds = 1KB/wave
    int offw = wave * 1024 + lane * 16;     // byte pos within 8KB half
    int rih  = offw >> 6;                   // row in half (0..127)
    long colswz = (long)(((lane & 3) ^ ((rih >> 1) & 3)) << 4);  // inverse-swizzled source slot
    long rowbA0 = (long)rih * ldab, rowbA1 = (long)(rih + 128) * ldab;
    long rowbB0 = (long)rih * ldbb, rowbB1 = (long)(rih + 128) * ldbb;
    int ldsoff = wave * 1024;

    auto STA = [&](int t, int h, int buf) {
        gld_lds16(Ab + (h ? rowbA1 : rowbA0) + (long)t * 64 + colswz,
                  (char*)As + buf * 16384 + h * 8192 + ldsoff);
    };
    auto STB = [&](int t, int h, int buf) {
        gld_lds16(Bb + (h ? rowbB1 : rowbB0) + (long)t * 64 + colswz,
                  (char*)Bs + buf * 16384 + h * 8192 + ldsoff);
    };

    // ---- fragment read byte-offsets (swizzled), loop-invariant
    int aoff[8], boff[4];
#pragma unroll
    for (int m = 0; m < 8; ++m) {
        int row = wm * 128 + m * 16 + lr;
        aoff[m] = (row * 64 + kc * 16) ^ (((row >> 1) & 3) << 4);
    }
#pragma unroll
    for (int n = 0; n < 4; ++n) {
        int row = wn * 64 + n * 16 + lr;
        boff[n] = (row * 64 + kc * 16) ^ (((row >> 1) & 3) << 4);
    }

    f32x4 acc[8][4];
#pragma unroll
    for (int m = 0; m < 8; ++m)
#pragma unroll
        for (int n = 0; n < 4; ++n) acc[m][n] = (f32x4){0.f, 0.f, 0.f, 0.f};

    // ---- prologue: tiles 0 and 1 fully staged; wait tile0 (tile1's 4 in flight)
    STA(0, 0, 0); STA(0, 1, 0); STB(0, 0, 0); STB(0, 1, 0);
    STA(1, 0, 1); STA(1, 1, 1); STB(1, 0, 1); STB(1, 1, 1);
    asm volatile("s_waitcnt vmcnt(4)" ::: "memory");
    __builtin_amdgcn_s_barrier();

    int cur = 0;

    for (int t = 0; t < NT; ++t) {
        int b2 = cur + 2; if (b2 >= 3) b2 -= 3;       // buf for tile t+2 (holds dead t-1)
        int t2 = (t + 2 < NT) ? (t + 2) : NT - 1;     // tail: redundant re-stage (never read)
        const char* Ac = (const char*)As + cur * 16384;
        const char* Bc = (const char*)Bs + cur * 16384;

        bf16x8 alo[4], ahi[4], bfr[4];
#pragma unroll
        for (int m = 0; m < 4; ++m) alo[m] = *(const bf16x8*)(Ac + aoff[m]);
#pragma unroll
        for (int n = 0; n < 4; ++n) bfr[n] = *(const bf16x8*)(Bc + boff[n]);
#pragma unroll
        for (int m = 0; m < 4; ++m) ahi[m] = *(const bf16x8*)(Ac + aoff[m + 4]);

        STA(t2, 0, b2); STA(t2, 1, b2);
        STB(t2, 0, b2); STB(t2, 1, b2);
        __builtin_amdgcn_sched_barrier(0);   // keep reads+stages above the MFMA cluster

        __builtin_amdgcn_s_setprio(1);
#pragma unroll
        for (int m = 0; m < 4; ++m)
#pragma unroll
            for (int n = 0; n < 4; ++n)
                acc[m][n] = __builtin_amdgcn_mfma_f32_16x16x32_bf16(alo[m], bfr[n], acc[m][n], 0, 0, 0);
#pragma unroll
        for (int m = 0; m < 4; ++m)
#pragma unroll
            for (int n = 0; n < 4; ++n)
                acc[m + 4][n] = __builtin_amdgcn_mfma_f32_16x16x32_bf16(ahi[m], bfr[n], acc[m + 4][n], 0, 0, 0);
        __builtin_amdgcn_s_setprio(0);

        asm volatile("s_waitcnt vmcnt(4)" ::: "memory");   // t+1 landed; t+2 stays in flight
        __builtin_amdgcn_s_barrier();

        cur += 1; if (cur >= 3) cur -= 3;
    }

    asm volatile("s_waitcnt vmcnt(0)" ::: "memory");

    // ---- epilogue: D[row=(lane>>4)*4+r][col=lane&15] per 16x16 fragment
#pragma unroll
    for (int m = 0; m < 8; ++m) {
        long row = bm0 + wm * 128 + m * 16 + kc * 4;
#pragma unroll
        for (int n = 0; n < 4; ++n) {
            long col = bn0 + wn * 64 + n * 16 + lr;
            float bv = bias ? bias[col] : 0.f;
            if (Vt && col >= vsplit) {
                // transposed V write: 4 acc rows = 4 consecutive tokens at
                // one channel -> one aligned 8B store into Vt[b][c][t].
                // (col uniform per fragment vs vsplit: both 16-aligned.)
                long bb = row >> 11;            // T = 2048
                long tl = row & 2047;
                ushort4 pk;
                pk.x = bf16_bits(acc[m][n][0] * scale + bv);
                pk.y = bf16_bits(acc[m][n][1] * scale + bv);
                pk.z = bf16_bits(acc[m][n][2] * scale + bv);
                pk.w = bf16_bits(acc[m][n][3] * scale + bv);
                *reinterpret_cast<ushort4*>(
                    Vt + bb * 2097152 + (col - vsplit) * 2048 + tl) = pk;
            } else if (c_f32) {
                float* Crow = (float*)Cp + (long)b * strideC;
#pragma unroll
                for (int r = 0; r < 4; ++r)
                    Crow[(row + r) * ldc + col] = acc[m][n][r] * scale + bv;
            } else {
                bf16_t* Crow = (bf16_t*)Cp + (long)b * strideC;
#pragma unroll
                for (int r = 0; r < 4; ++r)
                    Crow[(row + r) * ldc + col] = __float2bfloat16(acc[m][n][r] * scale + bv);
            }
        }
    }
}

// ---------------------------------------------------------------- causal softmax (in-place, bf16)
// Traffic-trimmed: skip loads where s0 > t, skip stores at cols >= klim
// (PV's causal K-limit means they are never read).

__global__ __launch_bounds__(256) void softmax_causal_kernel(bf16_t* S, int T) {
    int t = blockIdx.x;
    bf16_t* row = S + ((long)blockIdx.y * T + t) * (long)T;
    int tid = threadIdx.x;
    int s0 = tid * 8;
    int klim = ((t >> 8) + 1) << 8;

    u16x8 raw = {};
    if (s0 <= t) raw = *reinterpret_cast<const u16x8*>(&row[s0]);
    float v[8];
#pragma unroll
    for (int j = 0; j < 8; ++j) v[j] = __uint_as_float(((unsigned)raw[j]) << 16);

    float m = -1e30f;
#pragma unroll
    for (int j = 0; j < 8; ++j)
        if (s0 + j <= t) m = fmaxf(m, v[j]);

    __shared__ float red[8];
#pragma unroll
    for (int o = 32; o; o >>= 1) m = fmaxf(m, __shfl_xor(m, o, 64));
    if ((tid & 63) == 0) red[tid >> 6] = m;
    __syncthreads();
    m = fmaxf(fmaxf(red[0], red[1]), fmaxf(red[2], red[3]));
    __syncthreads();

    float e[8];
    float sum = 0.f;
#pragma unroll
    for (int j = 0; j < 8; ++j) {
        e[j] = (s0 + j <= t) ? __expf(v[j] - m) : 0.f;
        sum += e[j];
    }
#pragma unroll
    for (int o = 32; o; o >>= 1) sum += __shfl_xor(sum, o, 64);
    if ((tid & 63) == 0) red[tid >> 6] = sum;
    __syncthreads();
    sum = red[0] + red[1] + red[2] + red[3];
    float inv = 1.f / sum;

    if (s0 < klim) {
        u16x8 outp;
#pragma unroll
        for (int j = 0; j < 8; ++j) outp[j] = bf16_bits(e[j] * inv);
        *reinterpret_cast<u16x8*>(&row[s0]) = outp;
    }
}

// ---------------------------------------------------------------- launch

extern "C" void kernel_launch(void* const* d_in, const int* in_sizes, int n_in,
                              void* d_out, int out_size, void* d_ws, size_t ws_size,
                              hipStream_t stream) {
    const int B = 8, T = 2048, C = 1024;
    const int M = B * T;            // 16384
    const int N3 = 3 * C;           // 3072

    const float* x      = (const float*)d_in[0];
    const float* w_attn = (const float*)d_in[1];
    const float* b_attn = (const float*)d_in[2];
    const float* w_proj = (const float*)d_in[3];
    const float* b_proj = (const float*)d_in[4];
    float* out = (float*)d_out;     // reference output dtype is fp32

    char* ws = (char*)d_ws;

    // ---- adaptive workspace tiering ----
    // chunked: weights 8.4 + qkv 100.7 + xbO 33.5 + vT(full) 33.5 + NB*S 8.4
    const size_t BASE_FULL = 176160768ull;
    const size_t PER_B     = 8388608ull;
    long NB = 0;
    if (ws_size >= BASE_FULL + PER_B) {
        NB = (long)((ws_size - BASE_FULL) / PER_B);
        if (NB > 8) NB = 8;
    }

    if (NB >= 1) {
        // ---------------- chunked path
        bf16_t* waT = (bf16_t*)(ws);                    // [3C, C]   6.3 MB
        bf16_t* wpT = (bf16_t*)(ws + 6291456);          // [C, C]    2.1 MB
        bf16_t* qkv = (bf16_t*)(ws + 8388608);          // [M, 3C] 100.7 MB (V cols unwritten)
        bf16_t* xbO = (bf16_t*)(ws + 109051904);        // [M, C]   33.5 MB (xb, then O)
        bf16_t* vT  = (bf16_t*)(ws + 142606336);        // [B, C, T] 33.5 MB (fused transposed V)
        bf16_t* S   = (bf16_t*)(ws + 176160768);        // [NB, T, T]

        cvt_f32_bf16_kernel<<<2048, 256, 0, stream>>>(x, xbO, (long)M * C / 4);

        transpose_f32_bf16_kernel<<<dim3(N3 / 32, C / 32, 1), dim3(32, 8), 0, stream>>>(
            w_attn, waT, N3, C);
        transpose_f32_bf16_kernel<<<dim3(C / 32, C / 32, 1), dim3(32, 8), 0, stream>>>(
            w_proj, wpT, C, C);

        // qkv = xb @ w_attn + b_attn  (panel swizzle; V cols -> vT transposed)
        gemm256_kernel<<<dim3((M / 256) * (N3 / 256), 1, 1), 512, 0, stream>>>(
            xbO, waT, qkv, b_attn, 1.0f, C,
            C, C, N3, 0, 0, 0, M / 256, 0, 0, 0, 1, vT, 2 * C);

        for (long b0 = 0; b0 < B; b0 += NB) {
            long nb = (B - b0 < NB) ? (B - b0) : NB;
            const bf16_t* qkv_c = qkv + b0 * (long)T * N3;
            bf16_t* O_c = xbO + b0 * (long)T * C;

            // S = (Q K^T)/sqrt(C), causal block-skip (balanced swizzle)
            gemm256_kernel<<<dim3((T / 256) * (T / 256), 1, nb), 512, 0, stream>>>(
                qkv_c, qkv_c + C, S, nullptr, 0.03125f, C,
                N3, N3, T, (long)T * N3, (long)T * N3, (long)T * T, T / 256, 1, 0, 0, 0,
                nullptr, 0);

            softmax_causal_kernel<<<dim3(T, nb), 256, 0, stream>>>(S, T);

            // O = P @ V, causal K-limit (balanced swizzle)
            gemm256_kernel<<<dim3((T / 256) * (C / 256), 1, nb), 512, 0, stream>>>(
                S, vT + b0 * (long)C * T, O_c, nullptr, 1.0f, T,
                T, T, C, (long)T * T, (long)C * T, (long)T * C, T / 256, 0, 1, 0, 0,
                nullptr, 0);
        }

        // out = O @ w_proj + b_proj   (fp32 store, panel swizzle)
        gemm256_kernel<<<dim3((M / 256) * (C / 256), 1, 1), 512, 0, stream>>>(
            xbO, wpT, out, b_proj, 1.0f, C,
            C, C, C, 0, 0, 0, M / 256, 0, 0, 1, 1, nullptr, 0);
    } else {
        // ---------------- per-batch fallback (36 MB total, unfused V)
        bf16_t* waT  = (bf16_t*)(ws);                   // [3C, C]   6.3 MB
        bf16_t* wpT  = (bf16_t*)(ws + 6291456);         // [C, C]    2.1 MB
        bf16_t* xbO  = (bf16_t*)(ws + 8388608);         // [T, C]    4.2 MB
        bf16_t* qkvb = (bf16_t*)(ws + 12582912);        // [T, 3C]  12.6 MB
        bf16_t* vTb  = (bf16_t*)(ws + 25165824);        // [C, T]    4.2 MB
        bf16_t* Sb   = (bf16_t*)(ws + 29360128);        // [T, T]    8.4 MB

        transpose_f32_bf16_kernel<<<dim3(N3 / 32, C / 32, 1), dim3(32, 8), 0, stream>>>(
            w_attn, waT, N3, C);
        transpose_f32_bf16_kernel<<<dim3(C / 32, C / 32, 1), dim3(32, 8), 0, stream>>>(
            w_proj, wpT, C, C);

        for (int b = 0; b < B; ++b) {
            const float* x_b = x + (long)b * T * C;
            float* out_b = out + (long)b * T * C;

            cvt_f32_bf16_kernel<<<1024, 256, 0, stream>>>(x_b, xbO, (long)T * C / 4);

            gemm256_kernel<<<dim3((T / 256) * (N3 / 256), 1, 1), 512, 0, stream>>>(
                xbO, waT, qkvb, b_attn, 1.0f, C,
                C, C, N3, 0, 0, 0, T / 256, 0, 0, 0, 1, nullptr, 0);

            transpose_bf16_kernel<<<dim3(C / 32, T / 32, 1), dim3(32, 8), 0, stream>>>(
                qkvb + 2 * C, vTb, N3, T, 0, 0);

            gemm256_kernel<<<dim3((T / 256) * (T / 256), 1, 1), 512, 0, stream>>>(
                qkvb, qkvb + C, Sb, nullptr, 0.03125f, C,
                N3, N3, T, 0, 0, 0, T / 256, 1, 0, 0, 0, nullptr, 0);

            softmax_causal_kernel<<<dim3(T, 1), 256, 0, stream>>>(Sb, T);

            gemm256_kernel<<<dim3((T / 256) * (C / 256), 1, 1), 512, 0, stream>>>(
                Sb, vTb, xbO, nullptr, 1.0f, T,
                T, T, C, 0, 0, 0, T / 256, 0, 1, 0, 0, nullptr, 0);

            gemm256_kernel<<<dim3((T / 256) * (C / 256), 1, 1), 512, 0, stream>>>(
                xbO, wpT, out_b, b_proj, 1.0f, C,
                C, C, C, 0, 0, 0, T / 256, 0, 0, 1, 1, nullptr, 0);
        }
    }
}